// Round 1
// baseline (172.730 us; speedup 1.0000x reference)
//
#include <hip/hip_runtime.h>

typedef _Float16 f16x8 __attribute__((ext_vector_type(8)));
typedef _Float16 f16x4t __attribute__((ext_vector_type(4)));
typedef __fp16 h16x2 __attribute__((ext_vector_type(2)));
typedef float f32x4 __attribute__((ext_vector_type(4)));
typedef float f32x16 __attribute__((ext_vector_type(16)));
typedef unsigned int uint2v __attribute__((ext_vector_type(2)));

#define L_SZ 4096

__device__ __forceinline__ unsigned short f2h(float f) {
    _Float16 h = (_Float16)f;
    return __builtin_bit_cast(unsigned short, h);
}
__device__ __forceinline__ unsigned int pk2(float a, float b) {
    h16x2 p = __builtin_amdgcn_cvt_pkrtz(a, b);
    return __builtin_bit_cast(unsigned int, p);
}

// LDS slot for 64-row x 8-chunk (16B) K/V tiles: chunk-major, row^chunk xor.
#define SLOT(row, ci) ((((ci) * 64) + ((row) & 32) + (((row) & 31) ^ (ci))) * 8)

// ---------------- K0: one-shot weight conversion to swizzled f16 images ----
// Wimg: qkv weights, o=0..383 rows of 128; Fimg: fc weights, o=0..127.
// Layout identical to the LDS image: img[o*128 + ((ci^(o&15))*8) + j].
__global__ __launch_bounds__(256) void prep_kernel(
    const float* __restrict__ wq, const float* __restrict__ wk,
    const float* __restrict__ wv, const float* __restrict__ fcw,
    unsigned short* __restrict__ Wimg, unsigned short* __restrict__ Fimg)
{
    int e2 = blockIdx.x * 256 + threadIdx.x;       // 0..32767 float2 elems
    if (e2 < 24576) {
        const float* src = (e2 < 8192) ? wq : (e2 < 16384 ? wk : wv);
        float2 v = *(const float2*)&src[(e2 * 2) & 16383];
        int e = e2 * 2;
        int o = e >> 7, ci = (e & 127) >> 3, j = e & 7;
        *(unsigned int*)&Wimg[o * 128 + ((ci ^ (o & 15)) * 8) + j] = pk2(v.x, v.y);
    } else {
        int fe = (e2 - 24576) * 2;
        float2 v = *(const float2*)&fcw[fe];
        int o = fe >> 7, ci = (fe & 127) >> 3, j = fe & 7;
        *(unsigned int*)&Fimg[o * 128 + ((ci ^ (o & 15)) * 8) + j] = pk2(v.x, v.y);
    }
}

// ---------------- K1: QKV projection (weights pre-converted) ---------------
__global__ __launch_bounds__(256, 1) void qkv_kernel(
    const float* __restrict__ x,
    const unsigned short* __restrict__ Wimg,
    const float* __restrict__ bq, const float* __restrict__ bk,
    const float* __restrict__ bv,
    unsigned short* __restrict__ Qp, unsigned short* __restrict__ Kp,
    unsigned short* __restrict__ Vp)
{
    int blk = blockIdx.x;
    int bidx = blk >> 6;
    int l0 = (blk & 63) * 64;
    int tid = threadIdx.x;
    int wave = tid >> 6, lane = tid & 63;
    int c = lane & 15, qd = lane >> 4;

    __shared__ __align__(16) unsigned short Ws[384 * 128]; // 96KB
    __shared__ __align__(16) unsigned short Sc[9216];      // union: Xs(8192) / Vt(128x72)

    // ---- weights: straight f16 copy from pre-swizzled image (24 x 4KB)
    #pragma unroll
    for (int t = 0; t < 24; ++t) {
        int i8 = (tid + t * 256) * 8;
        *(uint4*)&Ws[i8] = *(const uint4*)&Wimg[i8];
    }

    // ---- stage x tile into Xs
    unsigned short* Xs = Sc;
    #pragma unroll
    for (int it = 0; it < 8; ++it) {
        int i  = (tid >> 4) + 16 * it;
        int l4 = (tid & 15) * 4;
        const float4 v = *(const float4*)&x[(bidx * 128 + i) * L_SZ + l0 + l4];
        float vv[4] = {v.x, v.y, v.z, v.w};
        int ci = i >> 3;
        #pragma unroll
        for (int u = 0; u < 4; ++u) {
            int l = l4 + u;
            Xs[l * 128 + ((ci ^ (l & 15)) * 8) + (i & 7)] = f2h(vv[u]);
        }
    }
    __syncthreads();

    f16x8 afrag[4];
    #pragma unroll
    for (int kc = 0; kc < 4; ++kc) {
        int l = wave * 16 + c;
        int ci = kc * 4 + qd;
        afrag[kc] = *(const f16x8*)&Xs[l * 128 + ((ci ^ (l & 15)) * 8)];
    }
    __syncthreads();   // all Xs reads done before Vt overwrites Sc

    f32x4 acc[24];
    #pragma unroll
    for (int nt = 0; nt < 24; ++nt) acc[nt] = (f32x4){0.f, 0.f, 0.f, 0.f};

    #pragma unroll
    for (int kc = 0; kc < 4; ++kc) {
        #pragma unroll
        for (int nt = 0; nt < 24; ++nt) {
            int o = nt * 16 + c;   // 0..383, o&15 == c
            f16x8 bfrag = *(const f16x8*)&Ws[o * 128 + (((kc * 4 + qd) ^ c) * 8)];
            acc[nt] = __builtin_amdgcn_mfma_f32_16x16x32_f16(afrag[kc], bfrag, acc[nt], 0, 0, 0);
        }
    }

    unsigned short* Vt = Sc;   // [o][72] pad to break banks
    const float s_q = 0.18033688011f;  // log2(e)/8
    #pragma unroll
    for (int nt = 0; nt < 24; ++nt) {
        int p = nt >> 3;
        int o = (nt & 7) * 16 + c;     // 0..127
        int h = o >> 6, d = o & 63;
        #pragma unroll
        for (int r = 0; r < 4; ++r) {
            int ll = wave * 16 + qd * 4 + r;
            int l = l0 + ll;
            float val = acc[nt][r];
            if (p == 0) {
                val = (val + bq[o]) * s_q;
                Qp[((bidx * 2 + h) * L_SZ + l) * 64 + d] = f2h(val);
            } else if (p == 1) {
                val += bk[o];
                Kp[((bidx * 2 + h) * L_SZ + l) * 64 + d] = f2h(val);
            } else {
                val += bv[o];
                Vt[o * 72 + ll] = f2h(val);
            }
        }
    }
    __syncthreads();
    // cooperative coalesced V store: 128 rows x 64 l
    #pragma unroll
    for (int t = 0; t < 2; ++t) {
        int u = tid + t * 256;          // 0..511
        int row = u >> 2;               // 0..127
        int lc = (u & 3) * 16;          // 16 l (32B) per thread
        uint4 a0 = *(const uint4*)&Vt[row * 72 + lc];
        uint4 a1 = *(const uint4*)&Vt[row * 72 + lc + 8];
        *(uint4*)&Vp[(size_t)(bidx * 128 + row) * L_SZ + l0 + lc] = a0;
        *(uint4*)&Vp[(size_t)(bidx * 128 + row) * L_SZ + l0 + lc + 8] = a1;
    }
}

// ---------------- K2: flash attention -------------------------------------
// Grid 1024 = sp(4) x bh(8) x ltile(32). 4 waves x 32 q-rows.
// In-register P via pk2+permlane32_swap (no Ps LDS); defer-max rescale;
// LDS 32KB -> 4 blocks/CU, full grid resident in one shot.
__global__ __launch_bounds__(256, 4) void attn_kernel(
    const unsigned short* __restrict__ Qp, const unsigned short* __restrict__ Kp,
    const unsigned short* __restrict__ Vp,
    unsigned short* __restrict__ Opart, float* __restrict__ Mpart, float* __restrict__ Lpart)
{
    int raw = blockIdx.x;
    int blk = (raw & 7) * 128 + (raw >> 3);   // XCD swizzle: 128-block chunks/XCD
    int lt = blk & 31;
    int bh = (blk >> 5) & 7;
    int sp = blk >> 8;
    int l0 = lt * 128;
    int tid = threadIdx.x;
    int wave = tid >> 6, lane = tid & 63;
    int ln = lane & 31, hi = lane >> 5;
    int b = bh >> 1, h = bh & 1;

    __shared__ __align__(16) unsigned short Ks[2][4096];
    __shared__ __align__(16) unsigned short Vs[2][4096];

    const unsigned short* Qb = Qp + (size_t)bh * L_SZ * 64;
    const unsigned short* Kb = Kp + (size_t)bh * L_SZ * 64;
    const unsigned short* Vb = Vp + ((size_t)b * 128 + h * 64) * L_SZ;

    int lq = l0 + wave * 32 + ln;
    f16x8 qf[4];   // B-operand: n = q-row ln, k chunks
    #pragma unroll
    for (int kc = 0; kc < 4; ++kc)
        qf[kc] = *(const f16x8*)&Qb[(size_t)lq * 64 + kc * 16 + hi * 8];

    float m_st = -1e30f, lsum = 0.f;
    f32x16 acc0 = {}, acc1 = {};

    int urow = tid >> 3, uci = tid & 7;   // staging assignment
    int mglob = sp * 1024;

    uint4 kreg[2], vreg[2];
    // prologue: tile 0
    #pragma unroll
    for (int j = 0; j < 2; ++j) {
        int row = urow + j * 32;
        kreg[j] = *(const uint4*)&Kb[(size_t)(mglob + row) * 64 + uci * 8];
        vreg[j] = *(const uint4*)&Vb[(size_t)row * L_SZ + mglob + uci * 8];
    }
    #pragma unroll
    for (int j = 0; j < 2; ++j) {
        int row = urow + j * 32;
        *(uint4*)&Ks[0][SLOT(row, uci)] = kreg[j];
        *(uint4*)&Vs[0][SLOT(row, uci)] = vreg[j];
    }

    for (int it = 0; it < 16; ++it) {
        int cur = it & 1;
        __syncthreads();                       // buf[cur] ready for everyone
        if (it < 15) {                         // prefetch next tile to regs
            int m0 = mglob + (it + 1) * 64;
            #pragma unroll
            for (int j = 0; j < 2; ++j) {
                int row = urow + j * 32;
                kreg[j] = *(const uint4*)&Kb[(size_t)(m0 + row) * 64 + uci * 8];
                vreg[j] = *(const uint4*)&Vb[(size_t)row * L_SZ + m0 + uci * 8];
            }
        }

        __builtin_amdgcn_s_setprio(1);
        // S^T = K . Q^T
        f32x16 s0 = {}, s1 = {};
        #pragma unroll
        for (int kc = 0; kc < 4; ++kc) {
            int cd = kc * 2 + hi;
            f16x8 k0 = *(const f16x8*)&Ks[cur][SLOT(ln, cd)];
            f16x8 k1 = *(const f16x8*)&Ks[cur][SLOT(32 + ln, cd)];
            s0 = __builtin_amdgcn_mfma_f32_32x32x16_f16(k0, qf[kc], s0, 0, 0, 0);
            s1 = __builtin_amdgcn_mfma_f32_32x32x16_f16(k1, qf[kc], s1, 0, 0, 0);
        }

        // tree max (depth 5 instead of serial 31)
        float t[8];
        #pragma unroll
        for (int r = 0; r < 8; ++r)
            t[r] = fmaxf(fmaxf(s0[r], s0[r + 8]), fmaxf(s1[r], s1[r + 8]));
        t[0] = fmaxf(t[0], t[4]); t[1] = fmaxf(t[1], t[5]);
        t[2] = fmaxf(t[2], t[6]); t[3] = fmaxf(t[3], t[7]);
        float mx = fmaxf(fmaxf(t[0], t[1]), fmaxf(t[2], t[3]));
        mx = fmaxf(mx, __shfl_xor(mx, 32));

        // defer-max: only rescale when max grew past threshold (base-2 units).
        // Skipped => P bounded by 2^8 = 256, fine in f16.
        if (!__all(mx <= m_st + 8.0f)) {
            float mnew = fmaxf(m_st, mx);
            float alpha = exp2f(m_st - mnew);
            m_st = mnew;
            lsum *= alpha;
            #pragma unroll
            for (int r = 0; r < 16; ++r) { acc0[r] *= alpha; acc1[r] *= alpha; }
        }
        float rsum = 0.f;
        #pragma unroll
        for (int r = 0; r < 16; ++r) { float p = exp2f(s0[r] - m_st); s0[r] = p; rsum += p; }
        #pragma unroll
        for (int r = 0; r < 16; ++r) { float p = exp2f(s1[r] - m_st); s1[r] = p; rsum += p; }
        lsum += rsum;

        // O^T += V . P^T, P^T B-frag assembled in-register:
        // C-layout key row = (r&3)+8*(r>>2)+4*hi -> pair pk2(s[b],s[b+1]) with
        // pk2(s[b+4],s[b+5]) and permlane32_swap to split keys across hi halves.
        #pragma unroll
        for (int kc = 0; kc < 4; ++kc) {
            unsigned int a0, a1, a2, a3;
            if (kc == 0) {
                a0 = pk2(s0[0], s0[1]);  a1 = pk2(s0[2], s0[3]);
                a2 = pk2(s0[4], s0[5]);  a3 = pk2(s0[6], s0[7]);
            } else if (kc == 1) {
                a0 = pk2(s0[8], s0[9]);  a1 = pk2(s0[10], s0[11]);
                a2 = pk2(s0[12], s0[13]); a3 = pk2(s0[14], s0[15]);
            } else if (kc == 2) {
                a0 = pk2(s1[0], s1[1]);  a1 = pk2(s1[2], s1[3]);
                a2 = pk2(s1[4], s1[5]);  a3 = pk2(s1[6], s1[7]);
            } else {
                a0 = pk2(s1[8], s1[9]);  a1 = pk2(s1[10], s1[11]);
                a2 = pk2(s1[12], s1[13]); a3 = pk2(s1[14], s1[15]);
            }
            uint2v r02 = __builtin_amdgcn_permlane32_swap(a0, a2, false, false);
            uint2v r13 = __builtin_amdgcn_permlane32_swap(a1, a3, false, false);
            uint4 pw; pw.x = r02[0]; pw.y = r13[0]; pw.z = r02[1]; pw.w = r13[1];
            f16x8 pf = __builtin_bit_cast(f16x8, pw);
            int cd = kc * 2 + hi;
            f16x8 v0 = *(const f16x8*)&Vs[cur][SLOT(ln, cd)];
            f16x8 v1 = *(const f16x8*)&Vs[cur][SLOT(32 + ln, cd)];
            acc0 = __builtin_amdgcn_mfma_f32_32x32x16_f16(v0, pf, acc0, 0, 0, 0);
            acc1 = __builtin_amdgcn_mfma_f32_32x32x16_f16(v1, pf, acc1, 0, 0, 0);
        }
        __builtin_amdgcn_s_setprio(0);

        if (it < 15) {                         // stage next tile (buf free past barrier)
            #pragma unroll
            for (int j = 0; j < 2; ++j) {
                int row = urow + j * 32;
                *(uint4*)&Ks[cur ^ 1][SLOT(row, uci)] = kreg[j];
                *(uint4*)&Vs[cur ^ 1][SLOT(row, uci)] = vreg[j];
            }
        }
    }

    float l_tot = lsum + __shfl_xor(lsum, 32);
    unsigned short* Ow = Opart + (size_t)(sp * 8 + bh) * 64 * 4096;
    #pragma unroll
    for (int r = 0; r < 16; ++r) {
        int d0 = (r & 3) + 8 * (r >> 2) + 4 * hi;
        Ow[(size_t)d0 * 4096 + lq] = f2h(acc0[r]);
        Ow[(size_t)(32 + d0) * 4096 + lq] = f2h(acc1[r]);
    }
    if (hi == 0) {
        Mpart[(sp * 8 + bh) * 4096 + lq] = m_st;
        Lpart[(sp * 8 + bh) * 4096 + lq] = l_tot;
    }
}

// ---------------- K3: combine + fc + BN + PReLU ----------------------------
// Hoisted Opart gathers (issued before LDS staging), f16 weight image,
// XCD swizzle: one bh's 2MB Opart slice stays on one XCD L2.
__global__ __launch_bounds__(256, 1) void fc_kernel(
    const unsigned short* __restrict__ Opart, const float* __restrict__ Mp,
    const float* __restrict__ Lp, const unsigned short* __restrict__ Fimg,
    const float* __restrict__ fc_b, const float* __restrict__ bn_g,
    const float* __restrict__ bn_b, const float* __restrict__ bn_m,
    const float* __restrict__ bn_v, const float* __restrict__ prelu_a,
    float* __restrict__ out)
{
    int raw = blockIdx.x;
    int blk = (raw & 7) * 32 + (raw >> 3);    // 32-block chunks/XCD == one bh
    int r0 = blk * 64;
    int tid = threadIdx.x;
    int c0 = (r0 >> 5) & 127;              // even -> block never straddles heads
    int bh = (r0 >> 12) * 2 + (c0 >> 6);

    int wave = tid >> 6, lane = tid & 63;
    int c = lane & 15, qd = lane >> 4;
    int rw = r0 + wave * 16;
    int row = rw + c;
    int ch = (row >> 5) & 127, hh = row & 31, d = ch & 63;

    __shared__ __align__(16) unsigned short Fw[128 * 128];   // 32KB
    __shared__ __align__(16) unsigned short SclU[4096 * 4];  // 32KB

    // hoisted Opart gathers: global reads don't depend on LDS -> issue first,
    // latency hides under the staging loops below.
    uint4 ovr[4][4];
    #pragma unroll
    for (int kc = 0; kc < 4; ++kc) {
        int w0 = kc * 32 + qd * 8;
        #pragma unroll
        for (int s = 0; s < 4; ++s)
            ovr[kc][s] = *(const uint4*)&Opart[(size_t)(s * 8 + bh) * 262144 + (size_t)d * 4096 + hh * 128 + w0];
    }

    // scales: slot(l) = h*128 + ((w + h)&127)
    #pragma unroll
    for (int t = 0; t < 16; ++t) {
        int l = tid + t * 256;
        float m0 = Mp[(0 * 8 + bh) * 4096 + l], m1 = Mp[(1 * 8 + bh) * 4096 + l];
        float m2 = Mp[(2 * 8 + bh) * 4096 + l], m3 = Mp[(3 * 8 + bh) * 4096 + l];
        float mx = fmaxf(fmaxf(m0, m1), fmaxf(m2, m3));
        float a0 = exp2f(m0 - mx), a1 = exp2f(m1 - mx);
        float a2 = exp2f(m2 - mx), a3 = exp2f(m3 - mx);
        float den = a0 * Lp[(0 * 8 + bh) * 4096 + l] + a1 * Lp[(1 * 8 + bh) * 4096 + l]
                  + a2 * Lp[(2 * 8 + bh) * 4096 + l] + a3 * Lp[(3 * 8 + bh) * 4096 + l];
        float inv = 1.0f / den;
        int hl = l >> 7, ww = l & 127;
        int slot = hl * 128 + ((ww + hl) & 127);
        uint2 sc;
        sc.x = pk2(a0 * inv, a1 * inv);
        sc.y = pk2(a2 * inv, a3 * inv);
        *(uint2*)&SclU[slot * 4] = sc;
    }
    // fcw: straight f16 copy from pre-swizzled image (8 x 4KB)
    #pragma unroll
    for (int t = 0; t < 8; ++t) {
        int i8 = (tid + t * 256) * 8;
        *(uint4*)&Fw[i8] = *(const uint4*)&Fimg[i8];
    }
    __syncthreads();

    // A-frags: combine 4 splits with scales (from hoisted regs)
    f16x8 af[4];
    #pragma unroll
    for (int kc = 0; kc < 4; ++kc) {
        int w0 = kc * 32 + qd * 8;
        f16x8 ov0 = __builtin_bit_cast(f16x8, ovr[kc][0]);
        f16x8 ov1 = __builtin_bit_cast(f16x8, ovr[kc][1]);
        f16x8 ov2 = __builtin_bit_cast(f16x8, ovr[kc][2]);
        f16x8 ov3 = __builtin_bit_cast(f16x8, ovr[kc][3]);
        #pragma unroll
        for (int j = 0; j < 8; ++j) {
            int slot = hh * 128 + ((w0 + j + hh) & 127);
            f16x4t sc = *(const f16x4t*)&SclU[slot * 4];
            float v = (float)ov0[j] * (float)sc[0] + (float)ov1[j] * (float)sc[1]
                    + (float)ov2[j] * (float)sc[2] + (float)ov3[j] * (float)sc[3];
            af[kc][j] = (_Float16)v;
        }
    }

    f32x4 acc[8];
    #pragma unroll
    for (int nt = 0; nt < 8; ++nt) acc[nt] = (f32x4){0.f, 0.f, 0.f, 0.f};
    #pragma unroll
    for (int kc = 0; kc < 4; ++kc) {
        #pragma unroll
        for (int nt = 0; nt < 8; ++nt) {
            int o = nt * 16 + c;
            f16x8 bf = *(const f16x8*)&Fw[o * 128 + (((kc * 4 + qd) ^ c) * 8)];
            acc[nt] = __builtin_amdgcn_mfma_f32_16x16x32_f16(af[kc], bf, acc[nt], 0, 0, 0);
        }
    }

    float pa = prelu_a[0];
    #pragma unroll
    for (int r = 0; r < 4; ++r) {
        int orow = rw + qd * 4 + r;
        int chn = (orow >> 5) & 127;
        float g  = bn_g[chn] * rsqrtf(bn_v[chn] + 1e-5f);
        float mn = bn_m[chn], bt = bn_b[chn];
        #pragma unroll
        for (int nt = 0; nt < 8; ++nt) {
            int o = nt * 16 + c;
            float y = (acc[nt][r] + fc_b[o] - mn) * g + bt;
            y = y > 0.f ? y : pa * y;
            out[(size_t)orow * 128 + o] = y;
        }
    }
}

extern "C" void kernel_launch(void* const* d_in, const int* in_sizes, int n_in,
                              void* d_out, int out_size, void* d_ws, size_t ws_size,
                              hipStream_t stream) {
    const float* x     = (const float*)d_in[0];
    const float* wq    = (const float*)d_in[1];
    const float* bq    = (const float*)d_in[2];
    const float* wk    = (const float*)d_in[3];
    const float* bk    = (const float*)d_in[4];
    const float* wv    = (const float*)d_in[5];
    const float* bv    = (const float*)d_in[6];
    const float* fcw_f = (const float*)d_in[7];
    const float* fcb   = (const float*)d_in[8];
    const float* bn_g  = (const float*)d_in[9];
    const float* bn_b  = (const float*)d_in[10];
    const float* bn_m  = (const float*)d_in[11];
    const float* bn_v  = (const float*)d_in[12];
    const float* pa    = (const float*)d_in[13];
    float* out = (float*)d_out;

    unsigned short* Qp  = (unsigned short*)d_ws;
    unsigned short* Kp  = Qp + 8 * L_SZ * 64;
    unsigned short* Vp  = Kp + 8 * L_SZ * 64;
    unsigned short* Opart = Vp + 8 * L_SZ * 64;   // f16, 4*8*64*4096
    float* Mpart = (float*)(Opart + 4 * 8 * 64 * L_SZ);
    float* Lpart = Mpart + 4 * 8 * L_SZ;
    unsigned short* Wimg = (unsigned short*)(Lpart + 4 * 8 * L_SZ); // 384*128 f16
    unsigned short* Fimg = Wimg + 384 * 128;                        // 128*128 f16

    hipLaunchKernelGGL(prep_kernel, dim3(128),  dim3(256), 0, stream,
                       wq, wk, wv, fcw_f, Wimg, Fimg);
    hipLaunchKernelGGL(qkv_kernel,  dim3(256),  dim3(256), 0, stream,
                       x, Wimg, bq, bk, bv, Qp, Kp, Vp);
    hipLaunchKernelGGL(attn_kernel, dim3(1024), dim3(256), 0, stream,
                       Qp, Kp, Vp, Opart, Mpart, Lpart);
    hipLaunchKernelGGL(fc_kernel,   dim3(256),  dim3(256), 0, stream,
                       Opart, Mpart, Lpart, Fimg, fcb, bn_g, bn_b, bn_m, bn_v, pa, out);
}